// Round 4
// baseline (395.596 us; speedup 1.0000x reference)
//
#include <hip/hip_runtime.h>
#include <hip/hip_bf16.h>
#include <stdint.h>

#define NT   204800      // nodes
#define NE   3276800     // edges
#define ED   64          // embed dim
#define NBG  8192        // graphs
#define HID  1600        // 25*64
#define HPAD 1664        // 13*128
#define CAP  56          // per-node list capacity (Poisson(16) max indegree ~38)
#define NBKT 400         // dst>>9 -> 400 buckets of 512 nodes
#define BCAP 9216        // per-bucket record capacity (mean 8192, +11 sigma)

typedef float  f32x4  __attribute__((ext_vector_type(4)));
typedef __bf16 bf16x8 __attribute__((ext_vector_type(8)));

__device__ __forceinline__ void async_ld16(const void* g, void* l) {
    __builtin_amdgcn_global_load_lds(
        (__attribute__((address_space(1))) const void*)g,
        (__attribute__((address_space(3))) void*)l, 16, 0, 0);
}

// bf16 bits of a float (round-to-nearest-even via intrinsic, reinterpret raw)
__device__ __forceinline__ unsigned short f2bf_raw(float f) {
    __hip_bfloat16 h = __float2bfloat16(f);
    return *(unsigned short*)&h;
}

// ---------- init global bucket cursors to fixed bases ----------
__global__ void k_initg(int* __restrict__ gcur) {
    int t = threadIdx.x;
    if (t < NBKT) gcur[t] = t * BCAP;
}

// ---------- pass A: radix-partition edges into 400 dst-range buckets ----------
// ONE atomic pass: per-edge (localslot, rel, bucket) buffered in 25 registers
// during the histogram pass; records written after global cursor reservation.
// packed keep = (ls<<18) | (rel<<9) | b ; packed record = (src<<9) | rel
__global__ __launch_bounds__(256) void k_part(const int* __restrict__ srcv,
                                              const int* __restrict__ dstv,
                                              int* __restrict__ gcur,
                                              unsigned* __restrict__ rec) {
    __shared__ int hist[NBKT];
    __shared__ int gofs[NBKT];
    const int t = threadIdx.x;
    const int base = blockIdx.x * (NE / 512);   // 6400-edge chunk
    for (int i = t; i < NBKT; i += 256) hist[i] = 0;
    __syncthreads();
    unsigned keep[25];
#pragma unroll
    for (int j = 0; j < 25; ++j) {
        int d = dstv[base + j * 256 + t];
        int b = d >> 9;
        int ls = atomicAdd(&hist[b], 1);        // local slot within (block,bucket)
        keep[j] = ((unsigned)ls << 18) | ((unsigned)(d & 511) << 9) | (unsigned)b;
    }
    __syncthreads();
    for (int i = t; i < NBKT; i += 256) gofs[i] = atomicAdd(&gcur[i], hist[i]);
    __syncthreads();
#pragma unroll
    for (int j = 0; j < 25; ++j) {
        int s = srcv[base + j * 256 + t];
        unsigned k = keep[j];
        int b   = (int)(k & 511u);
        int rel = (int)((k >> 9) & 511u);
        int idx = gofs[b] + (int)(k >> 18);
        if (idx < (b + 1) * BCAP)   // overflow guard (P ~ 0)
            rec[idx] = ((unsigned)s << 9) | (unsigned)rel;
    }
}

// ---------- pass B: bucket-local CSR fill (LDS int counters) + dinv ----------
// 400 blocks x 512 threads; every record in bucket b belongs to this block.
__global__ __launch_bounds__(512) void k_fillb(const int* __restrict__ gcur,
                                               const unsigned* __restrict__ rec,
                                               int* __restrict__ cur,
                                               int* __restrict__ csr,
                                               float* __restrict__ dinv) {
    __shared__ int cnt[512];
    const int t = threadIdx.x;
    const int b = blockIdx.x;
    const int n0 = b * 512;
    cnt[t] = 0;
    __syncthreads();
    const int bstart = b * BCAP;
    int bcnt = gcur[b] - bstart;
    bcnt = (bcnt > BCAP) ? BCAP : bcnt;
    for (int idx = t; idx < bcnt; idx += 512) {
        unsigned r = rec[bstart + idx];
        unsigned rel = r & 511u;
        int ls = atomicAdd(&cnt[rel], 1);
        if (ls < CAP) csr[(size_t)(n0 + rel) * CAP + ls] = (int)(r >> 9);
    }
    __syncthreads();
    int cn = cnt[t];
    cur[n0 + t] = cn;
    dinv[n0 + t] = rsqrtf((float)cn + 1.f);   // +1 self-loop
}

// ---------- hbs = bf16( (x @ W_conv) * dinv[row] )  (bf16 MFMA, 64x64x64 tile) ----------
__global__ __launch_bounds__(256) void k_gemm_conv(const float* __restrict__ x,
                                                   const float* __restrict__ Wc,
                                                   const float* __restrict__ dinv,
                                                   __hip_bfloat16* __restrict__ hbs) {
    __shared__ unsigned short Xs[64 * 72];   // [row][k] bf16, padded
    __shared__ unsigned short Wt[64 * 72];   // [n][k] bf16 (Wc transposed), padded
    const int t = threadIdx.x;
    const int row0 = blockIdx.x * 64;
#pragma unroll
    for (int i = 0; i < 4; ++i) {
        int idx = i * 256 + t;                 // f32x4 units, 0..1023
        int r = idx >> 4, c4 = (idx & 15) << 2;
        // stage Wc transposed (bf16)
        f32x4 wv = ((const f32x4*)Wc)[idx];    // Wc[r][c4..c4+3]
        Wt[(c4 + 0) * 72 + r] = f2bf_raw(wv.x);
        Wt[(c4 + 1) * 72 + r] = f2bf_raw(wv.y);
        Wt[(c4 + 2) * 72 + r] = f2bf_raw(wv.z);
        Wt[(c4 + 3) * 72 + r] = f2bf_raw(wv.w);
        // stage X as bf16
        f32x4 xv = ((const f32x4*)(x + (size_t)row0 * 64))[idx];
        ushort4 p;
        p.x = f2bf_raw(xv.x);
        p.y = f2bf_raw(xv.y);
        p.z = f2bf_raw(xv.z);
        p.w = f2bf_raw(xv.w);
        *(ushort4*)&Xs[r * 72 + c4] = p;
    }
    __syncthreads();
    const int w = t >> 6, lane = t & 63;
    const int fr = lane & 15, fq = lane >> 4;
    f32x4 acc[4] = {};
#pragma unroll
    for (int kb = 0; kb < 2; ++kb) {
        bf16x8 av = *(const bf16x8*)&Xs[(w * 16 + fr) * 72 + kb * 32 + fq * 8];
#pragma unroll
        for (int j = 0; j < 4; ++j) {
            bf16x8 bv = *(const bf16x8*)&Wt[(j * 16 + fr) * 72 + kb * 32 + fq * 8];
            acc[j] = __builtin_amdgcn_mfma_f32_16x16x32_bf16(av, bv, acc[j], 0, 0, 0);
        }
    }
    // C layout: col = lane&15 (fr), row = (lane>>4)*4 + reg (fq*4+r)
#pragma unroll
    for (int r = 0; r < 4; ++r) {
        int row = row0 + w * 16 + fq * 4 + r;
        float di = dinv[row];
        unsigned short* dst = (unsigned short*)&hbs[(size_t)row * 64];
#pragma unroll
        for (int j = 0; j < 4; ++j)
            dst[j * 16 + fr] = f2bf_raw(acc[j][r] * di);
    }
}

// ---------- gather: one wave per node, lane = channel (R1 form, best measured) ----------
// Hb[d] = bf16( relu( bc + dinv[d] * ( hbs[d] + sum_src hbs[src] ) ) )
// Edge list is wave-uniform -> readfirstlane(d) keeps indices on the SCALAR
// pipe (batched s_load); gather addr = uniform SGPR base + lane*2. Tail =
// one masked 16-chunk gathering the L1-hot self row for invalid slots
// (costs requests but zero HBM traffic; avoids serialized branch chunks),
// corrected afterwards with a single fmaf.
__global__ __launch_bounds__(256) void k_gather(const int* __restrict__ cur,
                                                const int* __restrict__ csr,
                                                const float* __restrict__ dinv,
                                                const __hip_bfloat16* __restrict__ hbs,
                                                const float* __restrict__ bc,
                                                __hip_bfloat16* __restrict__ Hb) {
    const int lane = threadIdx.x & 63;
    const int du = __builtin_amdgcn_readfirstlane(blockIdx.x * 4 + (threadIdx.x >> 6));
    const float di = dinv[du];
    int cn = cur[du];
    cn = (cn > CAP) ? CAP : cn;
    const int* __restrict__ lst = csr + (size_t)du * CAP;
    const float self = __bfloat162float(hbs[(size_t)du * ED + lane]);  // self-loop term
    float acc = self;
    int e = 0;
    for (; e + 16 <= cn; e += 16) {
#pragma unroll
        for (int q = 0; q < 16; ++q) {
            int s = lst[e + q];                                   // scalar (s_load)
            acc += __bfloat162float(hbs[(size_t)s * ED + lane]);  // uniform base + lane*2
        }
    }
    if (e < cn) {
        const int pad = e + 16 - cn;          // invalid slots in the masked chunk
#pragma unroll
        for (int q = 0; q < 16; ++q) {
            int s = (e + q < cn) ? lst[e + q] : du;   // uniform s_cselect; safe addr
            acc += __bfloat162float(hbs[(size_t)s * ED + lane]);
        }
        acc = fmaf(-(float)pad, self, acc);   // undo the pad self-row adds
    }
    Hb[(size_t)du * ED + lane] = __float2bfloat16(fmaxf(bc[lane] + di * acc, 0.f));
}

// ---------- W1 -> bf16, transposed [HPAD][HID] ----------
__global__ void k_convW1(const float* __restrict__ W1, __hip_bfloat16* __restrict__ Bt) {
    __shared__ float tile[64][65];
    const int t = threadIdx.x;
    const int k0 = blockIdx.x * 64;   // 25 tiles
    const int n0 = blockIdx.y * 64;   // 26 tiles (pad zero)
#pragma unroll
    for (int i = 0; i < 16; ++i) {
        int lin = i * 256 + t;
        int r = lin >> 6, c = lin & 63;
        int n = n0 + c;
        tile[r][c] = (n < HID) ? W1[(size_t)(k0 + r) * HID + n] : 0.f;
    }
    __syncthreads();
#pragma unroll
    for (int i = 0; i < 16; ++i) {
        int lin = i * 256 + t;
        int nn = lin >> 6, kk = lin & 63;
        Bt[(size_t)(n0 + nn) * HID + k0 + kk] = __float2bfloat16(tile[kk][nn]);
    }
}

// ---------- h2 = relu(Hb @ W1 + b1)  (bf16 MFMA, 128x128 tile, BK=32) ----------
// Double-buffered LDS, SINGLE barrier per K-step: stage tile k+1 into
// buf[1-p] BEFORE computing tile k from buf[p]; the implicit vmcnt(0) at the
// end-of-step barrier lands after the 16 MFMAs, so stage latency overlaps
// compute. Safe: each wave lgkm-drains its ds_reads of buf[p] before the
// barrier, so buf[p] may be overwritten next step.
// XCD-slab swizzle (bijective, 832%8==0): each XCD owns a 1024-row A-slab
// (3.3 MB, fits 4 MB per-XCD L2) across all N-tiles; within an XCD,
// consecutive blocks share the same B-panel.
// LDS source-side swizzle (T2 both-sides): slot ^= (row>>1)&3 applied on the
// global source column (stays in the same 64B chunk -> coalesced) and XORed
// into the ds_read address; 8-way read conflict -> 2-way (free).
__global__ __launch_bounds__(256) void k_gemm1(const __hip_bfloat16* __restrict__ A,
                                               const __hip_bfloat16* __restrict__ Bt,
                                               const float* __restrict__ b1,
                                               __hip_bfloat16* __restrict__ h2) {
    __shared__ unsigned short As[2][128 * 32];
    __shared__ unsigned short Bs[2][128 * 32];
    const int t = threadIdx.x;
    const int lane = t & 63;
    const int wave = t >> 6;
    const int lin = blockIdx.y * (NBG / 128) + blockIdx.x;   // hw dispatch order
    const int xc  = lin & 7;                                 // XCD
    const int pos = lin >> 3;                                // 0..103
    const int bm0 = (xc * 8 + (pos & 7)) * 128;              // XCD-contig A-slab
    const int bn0 = (pos >> 3) * 128;                        // 0..12
    const int wm = (wave >> 1) * 64;
    const int wn = (wave & 1) * 64;
    const int fr = lane & 15;
    const int fq = lane >> 4;
    const int sr = t >> 2;                     // staged row 0..63 (and +64 twin)
    // swizzled source column: LDS slot (t&3) of row sr holds global slot
    // (t&3) ^ ((sr>>1)&3). Rows sr and sr+64 share the same XOR term.
    const int scs = (((t & 3) ^ ((sr >> 1) & 3)) * 8);
    const __hip_bfloat16* ga0 = A + (size_t)(bm0 + sr) * HID + scs;
    const __hip_bfloat16* ga1 = A + (size_t)(bm0 + 64 + sr) * HID + scs;
    const __hip_bfloat16* gb0 = Bt + (size_t)(bn0 + sr) * HID + scs;
    const __hip_bfloat16* gb1 = Bt + (size_t)(bn0 + 64 + sr) * HID + scs;
    // read side: global slot fq of row r lives in LDS slot fq ^ ((r>>1)&3);
    // (r>>1)&3 == (fr>>1)&3 for rows wm+fr+i*16 (wm, i*16 multiples of 8)
    const int rdx = (fr >> 1) & 3;
    const int fao = (wm + fr) * 32 + (fq ^ rdx) * 8;
    const int fbo = (wn + fr) * 32 + (fq ^ rdx) * 8;
    f32x4 acc[4][4] = {};
    // prologue: stage K-tile 0 into buffer 0
    async_ld16(ga0, &As[0][t * 8]);  async_ld16(ga1, &As[0][(256 + t) * 8]);
    async_ld16(gb0, &Bs[0][t * 8]);  async_ld16(gb1, &Bs[0][(256 + t) * 8]);
    ga0 += 32; ga1 += 32; gb0 += 32; gb1 += 32;
    __syncthreads();
    const int NKT = HID / 32;                  // 50 K-tiles
#pragma unroll 2
    for (int kt = 0; kt < NKT - 1; ++kt) {
        const int pc = kt & 1;
        // prefetch K-tile kt+1 into the other buffer (overlaps with compute)
        unsigned short* dA = &As[pc ^ 1][0];
        unsigned short* dB = &Bs[pc ^ 1][0];
        async_ld16(ga0, dA + t * 8);  async_ld16(ga1, dA + (256 + t) * 8);
        async_ld16(gb0, dB + t * 8);  async_ld16(gb1, dB + (256 + t) * 8);
        ga0 += 32; ga1 += 32; gb0 += 32; gb1 += 32;
        // compute K-tile kt from buf[pc]
        const unsigned short* fa = &As[pc][fao];
        const unsigned short* fb = &Bs[pc][fbo];
        bf16x8 av[4], bv[4];
#pragma unroll
        for (int i = 0; i < 4; ++i) av[i] = *(const bf16x8*)(fa + i * 16 * 32);
#pragma unroll
        for (int j = 0; j < 4; ++j) bv[j] = *(const bf16x8*)(fb + j * 16 * 32);
#pragma unroll
        for (int i = 0; i < 4; ++i)
#pragma unroll
            for (int j = 0; j < 4; ++j)
                acc[i][j] = __builtin_amdgcn_mfma_f32_16x16x32_bf16(av[i], bv[j], acc[i][j], 0, 0, 0);
        __syncthreads();   // single barrier/step: drains prefetch vmcnt + own lgkm
    }
    {   // epilogue: K-tile NKT-1 (in buffer (NKT-1)&1 = 1)
        const int pe = (NKT - 1) & 1;
        const unsigned short* fa = &As[pe][fao];
        const unsigned short* fb = &Bs[pe][fbo];
        bf16x8 av[4], bv[4];
#pragma unroll
        for (int i = 0; i < 4; ++i) av[i] = *(const bf16x8*)(fa + i * 16 * 32);
#pragma unroll
        for (int j = 0; j < 4; ++j) bv[j] = *(const bf16x8*)(fb + j * 16 * 32);
#pragma unroll
        for (int i = 0; i < 4; ++i)
#pragma unroll
            for (int j = 0; j < 4; ++j)
                acc[i][j] = __builtin_amdgcn_mfma_f32_16x16x32_bf16(av[i], bv[j], acc[i][j], 0, 0, 0);
    }
#pragma unroll
    for (int j = 0; j < 4; ++j) {
        int n = bn0 + wn + j * 16 + fr;
        if (n < HID) {
            float bias = b1[n];
#pragma unroll
            for (int i = 0; i < 4; ++i) {
#pragma unroll
                for (int r = 0; r < 4; ++r) {
                    int m = bm0 + wm + i * 16 + fq * 4 + r;
                    float v = acc[i][j][r] + bias;
                    h2[(size_t)m * HID + n] = __float2bfloat16(fmaxf(v, 0.f));
                }
            }
        }
    }
}

// ---------- logits + softmax (one wave per graph) ----------
__global__ void k_head(const __hip_bfloat16* __restrict__ h2, const float* __restrict__ W2,
                       const float* __restrict__ b2, float* __restrict__ out) {
    int g = blockIdx.x * 4 + (threadIdx.x >> 6);
    int lane = threadIdx.x & 63;
    const __hip_bfloat16* row = h2 + (size_t)g * HID;
    float a0 = 0.f, a1 = 0.f;
#pragma unroll
    for (int i = 0; i < 25; ++i) {
        int k = i * 64 + lane;
        float hv = __bfloat162float(row[k]);
        float2 w = ((const float2*)W2)[k];
        a0 += hv * w.x;
        a1 += hv * w.y;
    }
#pragma unroll
    for (int off = 32; off > 0; off >>= 1) {
        a0 += __shfl_down(a0, off, 64);
        a1 += __shfl_down(a1, off, 64);
    }
    if (lane == 0) {
        float l0 = a0 + b2[0], l1 = a1 + b2[1];
        float mx = fmaxf(l0, l1);
        float e0 = expf(l0 - mx), e1 = expf(l1 - mx);
        float s = e0 + e1;
        out[2 * g]     = e0 / s;
        out[2 * g + 1] = e1 / s;
    }
}

extern "C" void kernel_launch(void* const* d_in, const int* in_sizes, int n_in,
                              void* d_out, int out_size, void* d_ws, size_t ws_size,
                              hipStream_t stream) {
    const float* x  = (const float*)d_in[0];
    const int*   ei = (const int*)d_in[1];
    // d_in[2] = batch (unused; reshape handles grouping)
    const float* Wc = (const float*)d_in[3];
    const float* bc = (const float*)d_in[4];
    const float* W1 = (const float*)d_in[5];
    const float* b1 = (const float*)d_in[6];
    const float* W2 = (const float*)d_in[7];
    const float* b2 = (const float*)d_in[8];
    float* out = (float*)d_out;

    const int* srcv = ei;
    const int* dstv = ei + NE;

    // workspace layout (bytes):
    //   cur  : [0,         819200)
    //   dinv : [819200,    1638400)
    //   gcur : [1638400,   1640000)
    //   csr  : [1642496,   47517696)    int[NT*CAP]
    //   rec  : [47517696,  62263296)    unsigned[NBKT*BCAP]; dead after k_fillb
    //     hbs: [47517696,  73732096)    bf16 conv out (pre-scaled), overlays dead rec
    //     h2 : [47517696,  73732096)    bf16, overlays dead hbs (after k_gather)
    //   Hb   : [73732096,  99946496)    bf16 gather out
    //   Bt   : [99946496,  105271296)   bf16 W1^T padded
    char* ws = (char*)d_ws;
    int*   cur  = (int*)ws;
    float* dinv = (float*)(ws + 819200);
    int*   gcur = (int*)(ws + 1638400);
    int*   csr  = (int*)(ws + 1642496);
    unsigned* rec = (unsigned*)(ws + 47517696);
    __hip_bfloat16* hbs = (__hip_bfloat16*)(ws + 47517696);
    __hip_bfloat16* h2  = (__hip_bfloat16*)(ws + 47517696);
    __hip_bfloat16* Hb  = (__hip_bfloat16*)(ws + 73732096);
    __hip_bfloat16* Bt  = (__hip_bfloat16*)(ws + 99946496);

    k_initg    <<<1, 512, 0, stream>>>(gcur);
    k_part     <<<512, 256, 0, stream>>>(srcv, dstv, gcur, rec);
    k_fillb    <<<NBKT, 512, 0, stream>>>(gcur, rec, cur, csr, dinv);
    k_gemm_conv<<<NT / 64, 256, 0, stream>>>(x, Wc, dinv, hbs);
    k_gather   <<<NT / 4, 256, 0, stream>>>(cur, csr, dinv, hbs, bc, Hb);
    k_convW1   <<<dim3(HID / 64, HPAD / 64), 256, 0, stream>>>(W1, Bt);
    k_gemm1    <<<dim3(NBG / 128, HPAD / 128), 256, 0, stream>>>(Hb, Bt, b1, h2);
    k_head     <<<NBG / 4, 256, 0, stream>>>(h2, W2, b2, out);
}

// Round 5
// 391.152 us; speedup vs baseline: 1.0114x; 1.0114x over previous
//
#include <hip/hip_runtime.h>
#include <hip/hip_bf16.h>
#include <stdint.h>

#define NT   204800      // nodes
#define NE   3276800     // edges
#define ED   64          // embed dim
#define NBG  8192        // graphs
#define HID  1600        // 25*64
#define HPAD 1664        // 13*128
#define CAP  56          // per-node list capacity (Poisson(16) max indegree ~38)
#define NBKT 400         // dst>>9 -> 400 buckets of 512 nodes
#define BCAP 9216        // per-bucket record capacity (mean 8192, +11 sigma)

typedef float  f32x4  __attribute__((ext_vector_type(4)));
typedef __bf16 bf16x8 __attribute__((ext_vector_type(8)));

__device__ __forceinline__ void async_ld16(const void* g, void* l) {
    __builtin_amdgcn_global_load_lds(
        (__attribute__((address_space(1))) const void*)g,
        (__attribute__((address_space(3))) void*)l, 16, 0, 0);
}

// bf16 bits of a float (round-to-nearest-even via intrinsic, reinterpret raw)
__device__ __forceinline__ unsigned short f2bf_raw(float f) {
    __hip_bfloat16 h = __float2bfloat16(f);
    return *(unsigned short*)&h;
}

// ---------- init global bucket cursors to fixed bases ----------
__global__ void k_initg(int* __restrict__ gcur) {
    int t = threadIdx.x;
    if (t < NBKT) gcur[t] = t * BCAP;
}

// ---------- pass A: radix-partition edges into 400 dst-range buckets ----------
// ONE atomic pass: per-edge (localslot, rel, bucket) buffered in 25 registers
// during the histogram pass; records written after global cursor reservation.
// packed keep = (ls<<18) | (rel<<9) | b ; packed record = (src<<9) | rel
__global__ __launch_bounds__(256) void k_part(const int* __restrict__ srcv,
                                              const int* __restrict__ dstv,
                                              int* __restrict__ gcur,
                                              unsigned* __restrict__ rec) {
    __shared__ int hist[NBKT];
    __shared__ int gofs[NBKT];
    const int t = threadIdx.x;
    const int base = blockIdx.x * (NE / 512);   // 6400-edge chunk
    for (int i = t; i < NBKT; i += 256) hist[i] = 0;
    __syncthreads();
    unsigned keep[25];
#pragma unroll
    for (int j = 0; j < 25; ++j) {
        int d = dstv[base + j * 256 + t];
        int b = d >> 9;
        int ls = atomicAdd(&hist[b], 1);        // local slot within (block,bucket)
        keep[j] = ((unsigned)ls << 18) | ((unsigned)(d & 511) << 9) | (unsigned)b;
    }
    __syncthreads();
    for (int i = t; i < NBKT; i += 256) gofs[i] = atomicAdd(&gcur[i], hist[i]);
    __syncthreads();
#pragma unroll
    for (int j = 0; j < 25; ++j) {
        int s = srcv[base + j * 256 + t];
        unsigned k = keep[j];
        int b   = (int)(k & 511u);
        int rel = (int)((k >> 9) & 511u);
        int idx = gofs[b] + (int)(k >> 18);
        if (idx < (b + 1) * BCAP)   // overflow guard (P ~ 0)
            rec[idx] = ((unsigned)s << 9) | (unsigned)rel;
    }
}

// ---------- pass B: bucket-local CSR fill (LDS int counters) + dinv ----------
// 400 blocks x 512 threads; every record in bucket b belongs to this block.
__global__ __launch_bounds__(512) void k_fillb(const int* __restrict__ gcur,
                                               const unsigned* __restrict__ rec,
                                               int* __restrict__ cur,
                                               int* __restrict__ csr,
                                               float* __restrict__ dinv) {
    __shared__ int cnt[512];
    const int t = threadIdx.x;
    const int b = blockIdx.x;
    const int n0 = b * 512;
    cnt[t] = 0;
    __syncthreads();
    const int bstart = b * BCAP;
    int bcnt = gcur[b] - bstart;
    bcnt = (bcnt > BCAP) ? BCAP : bcnt;
    for (int idx = t; idx < bcnt; idx += 512) {
        unsigned r = rec[bstart + idx];
        unsigned rel = r & 511u;
        int ls = atomicAdd(&cnt[rel], 1);
        if (ls < CAP) csr[(size_t)(n0 + rel) * CAP + ls] = (int)(r >> 9);
    }
    __syncthreads();
    int cn = cnt[t];
    cur[n0 + t] = cn;
    dinv[n0 + t] = rsqrtf((float)cn + 1.f);   // +1 self-loop
}

// ---------- hbs = bf16( (x @ W_conv) * dinv[row] )  (bf16 MFMA, 64x64x64 tile) ----------
__global__ __launch_bounds__(256) void k_gemm_conv(const float* __restrict__ x,
                                                   const float* __restrict__ Wc,
                                                   const float* __restrict__ dinv,
                                                   __hip_bfloat16* __restrict__ hbs) {
    __shared__ unsigned short Xs[64 * 72];   // [row][k] bf16, padded
    __shared__ unsigned short Wt[64 * 72];   // [n][k] bf16 (Wc transposed), padded
    const int t = threadIdx.x;
    const int row0 = blockIdx.x * 64;
#pragma unroll
    for (int i = 0; i < 4; ++i) {
        int idx = i * 256 + t;                 // f32x4 units, 0..1023
        int r = idx >> 4, c4 = (idx & 15) << 2;
        // stage Wc transposed (bf16)
        f32x4 wv = ((const f32x4*)Wc)[idx];    // Wc[r][c4..c4+3]
        Wt[(c4 + 0) * 72 + r] = f2bf_raw(wv.x);
        Wt[(c4 + 1) * 72 + r] = f2bf_raw(wv.y);
        Wt[(c4 + 2) * 72 + r] = f2bf_raw(wv.z);
        Wt[(c4 + 3) * 72 + r] = f2bf_raw(wv.w);
        // stage X as bf16
        f32x4 xv = ((const f32x4*)(x + (size_t)row0 * 64))[idx];
        ushort4 p;
        p.x = f2bf_raw(xv.x);
        p.y = f2bf_raw(xv.y);
        p.z = f2bf_raw(xv.z);
        p.w = f2bf_raw(xv.w);
        *(ushort4*)&Xs[r * 72 + c4] = p;
    }
    __syncthreads();
    const int w = t >> 6, lane = t & 63;
    const int fr = lane & 15, fq = lane >> 4;
    f32x4 acc[4] = {};
#pragma unroll
    for (int kb = 0; kb < 2; ++kb) {
        bf16x8 av = *(const bf16x8*)&Xs[(w * 16 + fr) * 72 + kb * 32 + fq * 8];
#pragma unroll
        for (int j = 0; j < 4; ++j) {
            bf16x8 bv = *(const bf16x8*)&Wt[(j * 16 + fr) * 72 + kb * 32 + fq * 8];
            acc[j] = __builtin_amdgcn_mfma_f32_16x16x32_bf16(av, bv, acc[j], 0, 0, 0);
        }
    }
    // C layout: col = lane&15 (fr), row = (lane>>4)*4 + reg (fq*4+r)
#pragma unroll
    for (int r = 0; r < 4; ++r) {
        int row = row0 + w * 16 + fq * 4 + r;
        float di = dinv[row];
        unsigned short* dst = (unsigned short*)&hbs[(size_t)row * 64];
#pragma unroll
        for (int j = 0; j < 4; ++j)
            dst[j * 16 + fr] = f2bf_raw(acc[j][r] * di);
    }
}

// ---------- gather: one wave per node, lane = channel (R1 form, best measured) ----------
// Hb[d] = bf16( relu( bc + dinv[d] * ( hbs[d] + sum_src hbs[src] ) ) )
// Edge list is wave-uniform -> readfirstlane(d) keeps indices on the SCALAR
// pipe (batched s_load); gather addr = uniform SGPR base + lane*2. Tail =
// one masked 16-chunk gathering the L1-hot self row for invalid slots
// (costs requests but zero HBM traffic; avoids serialized branch chunks),
// corrected afterwards with a single fmaf.
__global__ __launch_bounds__(256) void k_gather(const int* __restrict__ cur,
                                                const int* __restrict__ csr,
                                                const float* __restrict__ dinv,
                                                const __hip_bfloat16* __restrict__ hbs,
                                                const float* __restrict__ bc,
                                                __hip_bfloat16* __restrict__ Hb) {
    const int lane = threadIdx.x & 63;
    const int du = __builtin_amdgcn_readfirstlane(blockIdx.x * 4 + (threadIdx.x >> 6));
    const float di = dinv[du];
    int cn = cur[du];
    cn = (cn > CAP) ? CAP : cn;
    const int* __restrict__ lst = csr + (size_t)du * CAP;
    const float self = __bfloat162float(hbs[(size_t)du * ED + lane]);  // self-loop term
    float acc = self;
    int e = 0;
    for (; e + 16 <= cn; e += 16) {
#pragma unroll
        for (int q = 0; q < 16; ++q) {
            int s = lst[e + q];                                   // scalar (s_load)
            acc += __bfloat162float(hbs[(size_t)s * ED + lane]);  // uniform base + lane*2
        }
    }
    if (e < cn) {
        const int pad = e + 16 - cn;          // invalid slots in the masked chunk
#pragma unroll
        for (int q = 0; q < 16; ++q) {
            int s = (e + q < cn) ? lst[e + q] : du;   // uniform s_cselect; safe addr
            acc += __bfloat162float(hbs[(size_t)s * ED + lane]);
        }
        acc = fmaf(-(float)pad, self, acc);   // undo the pad self-row adds
    }
    Hb[(size_t)du * ED + lane] = __float2bfloat16(fmaxf(bc[lane] + di * acc, 0.f));
}

// ---------- W1 -> bf16, transposed [HPAD][HID] ----------
__global__ void k_convW1(const float* __restrict__ W1, __hip_bfloat16* __restrict__ Bt) {
    __shared__ float tile[64][65];
    const int t = threadIdx.x;
    const int k0 = blockIdx.x * 64;   // 25 tiles
    const int n0 = blockIdx.y * 64;   // 26 tiles (pad zero)
#pragma unroll
    for (int i = 0; i < 16; ++i) {
        int lin = i * 256 + t;
        int r = lin >> 6, c = lin & 63;
        int n = n0 + c;
        tile[r][c] = (n < HID) ? W1[(size_t)(k0 + r) * HID + n] : 0.f;
    }
    __syncthreads();
#pragma unroll
    for (int i = 0; i < 16; ++i) {
        int lin = i * 256 + t;
        int nn = lin >> 6, kk = lin & 63;
        Bt[(size_t)(n0 + nn) * HID + k0 + kk] = __float2bfloat16(tile[kk][nn]);
    }
}

// ---------- h2 = relu(Hb @ W1 + b1)  (bf16 MFMA, 128x128 tile, BK=32) ----------
// T4 pipeline: 2 LDS buffers, 2 tiles in flight, COUNTED vmcnt (never 0 in
// the steady-state loop) + raw s_barrier. Step k: wait vmcnt(4) (tile k's 4
// loads done, tile k+1's still in flight) + barrier; compute; lgkmcnt(0) +
// barrier (all waves done reading buf[p]); stage tile k+2 into buf[p] ->
// its loads get a FULL step (~2x compute) to land, vs __syncthreads' forced
// same-step vmcnt(0) drain. Waits are fused into the same asm block as the
// barrier ("memory" clobber) so LDS reads cannot hoist above the barrier.
// All branches block-uniform -> raw barriers safe.
// XCD-slab swizzle (bijective): each XCD owns a 1024-row A-slab (3.3 MB,
// fits 4 MB per-XCD L2). LDS source-side swizzle: slot ^= (row>>1)&3 on the
// global source column + XOR on the ds_read address (8-way -> 2-way, free).
__global__ __launch_bounds__(256) void k_gemm1(const __hip_bfloat16* __restrict__ A,
                                               const __hip_bfloat16* __restrict__ Bt,
                                               const float* __restrict__ b1,
                                               __hip_bfloat16* __restrict__ h2) {
    __shared__ unsigned short As[2][128 * 32];
    __shared__ unsigned short Bs[2][128 * 32];
    const int t = threadIdx.x;
    const int lane = t & 63;
    const int wave = t >> 6;
    const int lin = blockIdx.y * (NBG / 128) + blockIdx.x;   // hw dispatch order
    const int xc  = lin & 7;                                 // XCD
    const int pos = lin >> 3;                                // 0..103
    const int bm0 = (xc * 8 + (pos & 7)) * 128;              // XCD-contig A-slab
    const int bn0 = (pos >> 3) * 128;                        // 0..12
    const int wm = (wave >> 1) * 64;
    const int wn = (wave & 1) * 64;
    const int fr = lane & 15;
    const int fq = lane >> 4;
    const int sr = t >> 2;                     // staged row 0..63 (and +64 twin)
    // swizzled source column: LDS slot (t&3) of row sr holds global slot
    // (t&3) ^ ((sr>>1)&3). Rows sr and sr+64 share the same XOR term.
    const int scs = (((t & 3) ^ ((sr >> 1) & 3)) * 8);
    const __hip_bfloat16* ga0 = A + (size_t)(bm0 + sr) * HID + scs;
    const __hip_bfloat16* ga1 = A + (size_t)(bm0 + 64 + sr) * HID + scs;
    const __hip_bfloat16* gb0 = Bt + (size_t)(bn0 + sr) * HID + scs;
    const __hip_bfloat16* gb1 = Bt + (size_t)(bn0 + 64 + sr) * HID + scs;
    // read side: global slot fq of row r lives in LDS slot fq ^ ((r>>1)&3);
    // (r>>1)&3 == (fr>>1)&3 for rows wm+fr+i*16 (wm, i*16 multiples of 8)
    const int rdx = (fr >> 1) & 3;
    const int fao = (wm + fr) * 32 + (fq ^ rdx) * 8;
    const int fbo = (wn + fr) * 32 + (fq ^ rdx) * 8;
    f32x4 acc[4][4] = {};

#define STAGE(bidx) do { \
        unsigned short* dA_ = &As[bidx][0]; unsigned short* dB_ = &Bs[bidx][0]; \
        async_ld16(ga0, dA_ + t * 8);  async_ld16(ga1, dA_ + (256 + t) * 8); \
        async_ld16(gb0, dB_ + t * 8);  async_ld16(gb1, dB_ + (256 + t) * 8); \
        ga0 += 32; ga1 += 32; gb0 += 32; gb1 += 32; } while (0)

    const int NKT = HID / 32;                  // 50 K-tiles
    // prologue: tiles 0 and 1 in flight (8 vmem ops/wave)
    STAGE(0);
    STAGE(1);
#pragma unroll 2
    for (int kt = 0; kt < NKT; ++kt) {
        const int p = kt & 1;
        // tile kt's 4 loads complete (tile kt+1 stays in flight); all waves sync
        if (kt < NKT - 1)
            asm volatile("s_waitcnt vmcnt(4)\n\ts_barrier" ::: "memory");
        else
            asm volatile("s_waitcnt vmcnt(0)\n\ts_barrier" ::: "memory");
        const unsigned short* fa = &As[p][fao];
        const unsigned short* fb = &Bs[p][fbo];
        bf16x8 av[4], bv[4];
#pragma unroll
        for (int i = 0; i < 4; ++i) av[i] = *(const bf16x8*)(fa + i * 16 * 32);
#pragma unroll
        for (int j = 0; j < 4; ++j) bv[j] = *(const bf16x8*)(fb + j * 16 * 32);
#pragma unroll
        for (int i = 0; i < 4; ++i)
#pragma unroll
            for (int j = 0; j < 4; ++j)
                acc[i][j] = __builtin_amdgcn_mfma_f32_16x16x32_bf16(av[i], bv[j], acc[i][j], 0, 0, 0);
        if (kt < NKT - 2) {
            // all waves finished their ds_reads of buf[p] -> safe to overwrite
            asm volatile("s_waitcnt lgkmcnt(0)\n\ts_barrier" ::: "memory");
            STAGE(p);                          // tile kt+2 (parity == p)
        }
    }
#undef STAGE

#pragma unroll
    for (int j = 0; j < 4; ++j) {
        int n = bn0 + wn + j * 16 + fr;
        if (n < HID) {
            float bias = b1[n];
#pragma unroll
            for (int i = 0; i < 4; ++i) {
#pragma unroll
                for (int r = 0; r < 4; ++r) {
                    int m = bm0 + wm + i * 16 + fq * 4 + r;
                    float v = acc[i][j][r] + bias;
                    h2[(size_t)m * HID + n] = __float2bfloat16(fmaxf(v, 0.f));
                }
            }
        }
    }
}

// ---------- logits + softmax (one wave per graph) ----------
__global__ void k_head(const __hip_bfloat16* __restrict__ h2, const float* __restrict__ W2,
                       const float* __restrict__ b2, float* __restrict__ out) {
    int g = blockIdx.x * 4 + (threadIdx.x >> 6);
    int lane = threadIdx.x & 63;
    const __hip_bfloat16* row = h2 + (size_t)g * HID;
    float a0 = 0.f, a1 = 0.f;
#pragma unroll
    for (int i = 0; i < 25; ++i) {
        int k = i * 64 + lane;
        float hv = __bfloat162float(row[k]);
        float2 w = ((const float2*)W2)[k];
        a0 += hv * w.x;
        a1 += hv * w.y;
    }
#pragma unroll
    for (int off = 32; off > 0; off >>= 1) {
        a0 += __shfl_down(a0, off, 64);
        a1 += __shfl_down(a1, off, 64);
    }
    if (lane == 0) {
        float l0 = a0 + b2[0], l1 = a1 + b2[1];
        float mx = fmaxf(l0, l1);
        float e0 = expf(l0 - mx), e1 = expf(l1 - mx);
        float s = e0 + e1;
        out[2 * g]     = e0 / s;
        out[2 * g + 1] = e1 / s;
    }
}

extern "C" void kernel_launch(void* const* d_in, const int* in_sizes, int n_in,
                              void* d_out, int out_size, void* d_ws, size_t ws_size,
                              hipStream_t stream) {
    const float* x  = (const float*)d_in[0];
    const int*   ei = (const int*)d_in[1];
    // d_in[2] = batch (unused; reshape handles grouping)
    const float* Wc = (const float*)d_in[3];
    const float* bc = (const float*)d_in[4];
    const float* W1 = (const float*)d_in[5];
    const float* b1 = (const float*)d_in[6];
    const float* W2 = (const float*)d_in[7];
    const float* b2 = (const float*)d_in[8];
    float* out = (float*)d_out;

    const int* srcv = ei;
    const int* dstv = ei + NE;

    // workspace layout (bytes):
    //   cur  : [0,         819200)
    //   dinv : [819200,    1638400)
    //   gcur : [1638400,   1640000)
    //   csr  : [1642496,   47517696)    int[NT*CAP]
    //   rec  : [47517696,  62263296)    unsigned[NBKT*BCAP]; dead after k_fillb
    //     hbs: [47517696,  73732096)    bf16 conv out (pre-scaled), overlays dead rec
    //     h2 : [47517696,  73732096)    bf16, overlays dead hbs (after k_gather)
    //   Hb   : [73732096,  99946496)    bf16 gather out
    //   Bt   : [99946496,  105271296)   bf16 W1^T padded
    char* ws = (char*)d_ws;
    int*   cur  = (int*)ws;
    float* dinv = (float*)(ws + 819200);
    int*   gcur = (int*)(ws + 1638400);
    int*   csr  = (int*)(ws + 1642496);
    unsigned* rec = (unsigned*)(ws + 47517696);
    __hip_bfloat16* hbs = (__hip_bfloat16*)(ws + 47517696);
    __hip_bfloat16* h2  = (__hip_bfloat16*)(ws + 47517696);
    __hip_bfloat16* Hb  = (__hip_bfloat16*)(ws + 73732096);
    __hip_bfloat16* Bt  = (__hip_bfloat16*)(ws + 99946496);

    k_initg    <<<1, 512, 0, stream>>>(gcur);
    k_part     <<<512, 256, 0, stream>>>(srcv, dstv, gcur, rec);
    k_fillb    <<<NBKT, 512, 0, stream>>>(gcur, rec, cur, csr, dinv);
    k_gemm_conv<<<NT / 64, 256, 0, stream>>>(x, Wc, dinv, hbs);
    k_gather   <<<NT / 4, 256, 0, stream>>>(cur, csr, dinv, hbs, bc, Hb);
    k_convW1   <<<dim3(HID / 64, HPAD / 64), 256, 0, stream>>>(W1, Bt);
    k_gemm1    <<<dim3(NBG / 128, HPAD / 128), 256, 0, stream>>>(Hb, Bt, b1, h2);
    k_head     <<<NBG / 4, 256, 0, stream>>>(h2, W2, b2, out);
}

// Round 7
// 376.147 us; speedup vs baseline: 1.0517x; 1.0399x over previous
//
#include <hip/hip_runtime.h>
#include <hip/hip_bf16.h>
#include <stdint.h>

#define NT   204800      // nodes
#define NE   3276800     // edges
#define ED   64          // embed dim
#define NBG  8192        // graphs
#define HID  1600        // 25*64
#define CAP  56          // per-node list capacity (Poisson(16) max indegree ~38)
#define NBKT 400         // dst>>9 -> 400 buckets of 512 nodes
#define BCAP 9216        // per-bucket record capacity (mean 8192, +11 sigma)

typedef float  f32x4  __attribute__((ext_vector_type(4)));
typedef __bf16 bf16x8 __attribute__((ext_vector_type(8)));

__device__ __forceinline__ void async_ld16(const void* g, void* l) {
    __builtin_amdgcn_global_load_lds(
        (__attribute__((address_space(1))) const void*)g,
        (__attribute__((address_space(3))) void*)l, 16, 0, 0);
}

// bf16 bits of a float (round-to-nearest-even via intrinsic, reinterpret raw)
__device__ __forceinline__ unsigned short f2bf_raw(float f) {
    __hip_bfloat16 h = __float2bfloat16(f);
    return *(unsigned short*)&h;
}

// ---------- init global bucket cursors to fixed bases ----------
__global__ void k_initg(int* __restrict__ gcur) {
    int t = threadIdx.x;
    if (t < NBKT) gcur[t] = t * BCAP;
}

// ---------- pass A: radix-partition edges into 400 dst-range buckets ----------
// ONE atomic pass: per-edge (localslot, rel, bucket) buffered in 25 registers
// during the histogram pass; records written after global cursor reservation.
// packed keep = (ls<<18) | (rel<<9) | b ; packed record = (src<<9) | rel
__global__ __launch_bounds__(256) void k_part(const int* __restrict__ srcv,
                                              const int* __restrict__ dstv,
                                              int* __restrict__ gcur,
                                              unsigned* __restrict__ rec) {
    __shared__ int hist[NBKT];
    __shared__ int gofs[NBKT];
    const int t = threadIdx.x;
    const int base = blockIdx.x * (NE / 512);   // 6400-edge chunk
    for (int i = t; i < NBKT; i += 256) hist[i] = 0;
    __syncthreads();
    unsigned keep[25];
#pragma unroll
    for (int j = 0; j < 25; ++j) {
        int d = dstv[base + j * 256 + t];
        int b = d >> 9;
        int ls = atomicAdd(&hist[b], 1);        // local slot within (block,bucket)
        keep[j] = ((unsigned)ls << 18) | ((unsigned)(d & 511) << 9) | (unsigned)b;
    }
    __syncthreads();
    for (int i = t; i < NBKT; i += 256) gofs[i] = atomicAdd(&gcur[i], hist[i]);
    __syncthreads();
#pragma unroll
    for (int j = 0; j < 25; ++j) {
        int s = srcv[base + j * 256 + t];
        unsigned k = keep[j];
        int b   = (int)(k & 511u);
        int rel = (int)((k >> 9) & 511u);
        int idx = gofs[b] + (int)(k >> 18);
        if (idx < (b + 1) * BCAP)   // overflow guard (P ~ 0)
            rec[idx] = ((unsigned)s << 9) | (unsigned)rel;
    }
}

// ---------- pass B: bucket-local CSR fill (LDS int counters) + dinv ----------
// 400 blocks x 512 threads; every record in bucket b belongs to this block.
__global__ __launch_bounds__(512) void k_fillb(const int* __restrict__ gcur,
                                               const unsigned* __restrict__ rec,
                                               int* __restrict__ cur,
                                               int* __restrict__ csr,
                                               float* __restrict__ dinv) {
    __shared__ int cnt[512];
    const int t = threadIdx.x;
    const int b = blockIdx.x;
    const int n0 = b * 512;
    cnt[t] = 0;
    __syncthreads();
    const int bstart = b * BCAP;
    int bcnt = gcur[b] - bstart;
    bcnt = (bcnt > BCAP) ? BCAP : bcnt;
    for (int idx = t; idx < bcnt; idx += 512) {
        unsigned r = rec[bstart + idx];
        unsigned rel = r & 511u;
        int ls = atomicAdd(&cnt[rel], 1);
        if (ls < CAP) csr[(size_t)(n0 + rel) * CAP + ls] = (int)(r >> 9);
    }
    __syncthreads();
    int cn = cnt[t];
    cur[n0 + t] = cn;
    dinv[n0 + t] = rsqrtf((float)cn + 1.f);   // +1 self-loop
}

// ---------- hbs = bf16( (x @ W_conv) * dinv[row] )  (bf16 MFMA, 64x64x64 tile) ----------
__global__ __launch_bounds__(256) void k_gemm_conv(const float* __restrict__ x,
                                                   const float* __restrict__ Wc,
                                                   const float* __restrict__ dinv,
                                                   __hip_bfloat16* __restrict__ hbs) {
    __shared__ unsigned short Xs[64 * 72];   // [row][k] bf16, padded
    __shared__ unsigned short Wt[64 * 72];   // [n][k] bf16 (Wc transposed), padded
    const int t = threadIdx.x;
    const int row0 = blockIdx.x * 64;
#pragma unroll
    for (int i = 0; i < 4; ++i) {
        int idx = i * 256 + t;                 // f32x4 units, 0..1023
        int r = idx >> 4, c4 = (idx & 15) << 2;
        // stage Wc transposed (bf16)
        f32x4 wv = ((const f32x4*)Wc)[idx];    // Wc[r][c4..c4+3]
        Wt[(c4 + 0) * 72 + r] = f2bf_raw(wv.x);
        Wt[(c4 + 1) * 72 + r] = f2bf_raw(wv.y);
        Wt[(c4 + 2) * 72 + r] = f2bf_raw(wv.z);
        Wt[(c4 + 3) * 72 + r] = f2bf_raw(wv.w);
        // stage X as bf16
        f32x4 xv = ((const f32x4*)(x + (size_t)row0 * 64))[idx];
        ushort4 p;
        p.x = f2bf_raw(xv.x);
        p.y = f2bf_raw(xv.y);
        p.z = f2bf_raw(xv.z);
        p.w = f2bf_raw(xv.w);
        *(ushort4*)&Xs[r * 72 + c4] = p;
    }
    __syncthreads();
    const int w = t >> 6, lane = t & 63;
    const int fr = lane & 15, fq = lane >> 4;
    f32x4 acc[4] = {};
#pragma unroll
    for (int kb = 0; kb < 2; ++kb) {
        bf16x8 av = *(const bf16x8*)&Xs[(w * 16 + fr) * 72 + kb * 32 + fq * 8];
#pragma unroll
        for (int j = 0; j < 4; ++j) {
            bf16x8 bv = *(const bf16x8*)&Wt[(j * 16 + fr) * 72 + kb * 32 + fq * 8];
            acc[j] = __builtin_amdgcn_mfma_f32_16x16x32_bf16(av, bv, acc[j], 0, 0, 0);
        }
    }
    // C layout: col = lane&15 (fr), row = (lane>>4)*4 + reg (fq*4+r)
#pragma unroll
    for (int r = 0; r < 4; ++r) {
        int row = row0 + w * 16 + fq * 4 + r;
        float di = dinv[row];
        unsigned short* dst = (unsigned short*)&hbs[(size_t)row * 64];
#pragma unroll
        for (int j = 0; j < 4; ++j)
            dst[j * 16 + fr] = f2bf_raw(acc[j][r] * di);
    }
}

// ---------- gather: one wave per node, lane = channel (R1 form, best measured) ----------
// Hb[d] = bf16( relu( bc + dinv[d] * ( hbs[d] + sum_src hbs[src] ) ) )
// Edge list is wave-uniform -> readfirstlane(d) keeps indices on the SCALAR
// pipe (batched s_load); gather addr = uniform SGPR base + lane*2. Tail =
// one masked 16-chunk gathering the L1-hot self row for invalid slots
// (costs requests but zero HBM traffic; avoids serialized branch chunks),
// corrected afterwards with a single fmaf.
__global__ __launch_bounds__(256) void k_gather(const int* __restrict__ cur,
                                                const int* __restrict__ csr,
                                                const float* __restrict__ dinv,
                                                const __hip_bfloat16* __restrict__ hbs,
                                                const float* __restrict__ bc,
                                                __hip_bfloat16* __restrict__ Hb) {
    const int lane = threadIdx.x & 63;
    const int du = __builtin_amdgcn_readfirstlane(blockIdx.x * 4 + (threadIdx.x >> 6));
    const float di = dinv[du];
    int cn = cur[du];
    cn = (cn > CAP) ? CAP : cn;
    const int* __restrict__ lst = csr + (size_t)du * CAP;
    const float self = __bfloat162float(hbs[(size_t)du * ED + lane]);  // self-loop term
    float acc = self;
    int e = 0;
    for (; e + 16 <= cn; e += 16) {
#pragma unroll
        for (int q = 0; q < 16; ++q) {
            int s = lst[e + q];                                   // scalar (s_load)
            acc += __bfloat162float(hbs[(size_t)s * ED + lane]);  // uniform base + lane*2
        }
    }
    if (e < cn) {
        const int pad = e + 16 - cn;          // invalid slots in the masked chunk
#pragma unroll
        for (int q = 0; q < 16; ++q) {
            int s = (e + q < cn) ? lst[e + q] : du;   // uniform s_cselect; safe addr
            acc += __bfloat162float(hbs[(size_t)s * ED + lane]);
        }
        acc = fmaf(-(float)pad, self, acc);   // undo the pad self-row adds
    }
    Hb[(size_t)du * ED + lane] = __float2bfloat16(fmaxf(bc[lane] + di * acc, 0.f));
}

// ---------- W1 -> bf16, transposed [HID][HID] ----------
__global__ void k_convW1(const float* __restrict__ W1, __hip_bfloat16* __restrict__ Bt) {
    __shared__ float tile[64][65];
    const int t = threadIdx.x;
    const int k0 = blockIdx.x * 64;   // 25 tiles
    const int n0 = blockIdx.y * 64;   // 25 tiles (no pad needed with 64-wide n-tiles)
#pragma unroll
    for (int i = 0; i < 16; ++i) {
        int lin = i * 256 + t;
        int r = lin >> 6, c = lin & 63;
        tile[r][c] = W1[(size_t)(k0 + r) * HID + n0 + c];
    }
    __syncthreads();
#pragma unroll
    for (int i = 0; i < 16; ++i) {
        int lin = i * 256 + t;
        int nn = lin >> 6, kk = lin & 63;
        Bt[(size_t)(n0 + nn) * HID + k0 + kk] = __float2bfloat16(tile[kk][nn]);
    }
}

// ---------- h2 = relu(Hb @ W1 + b1)  (bf16 MFMA, 128x64 tile, BK=32) ----------
// Occupancy fix: 1600 blocks (64 m-tiles x 25 n-tiles) = 6.25 blocks/CU,
// 25 waves/CU (~78% ceiling) vs the old 832-block/128x128 grid's 13 (40%).
// 25 n-tiles of 64 cover HID=1600 exactly -> pad tile and n-guard gone.
// T4 pipeline kept: 2 LDS buffers, 2 tiles (6 loads) in flight, counted
// vmcnt(3) in steady state (never 0 until the last tile), raw s_barrier
// fused into the same asm as the wait ("memory" clobber). Wave-uniform
// branches -> raw barriers safe.
// XCD slab swizzle (bijective, 1600%8==0): 8 m-tiles per XCD slab (1024 rows
// = 3.3 MB, fits 4 MB per-XCD L2); n-tile changes every 8 blocks.
// LDS source-side swizzle: slot ^= (row>>1)&3 on the global source column +
// XOR on the ds_read address (8-way read conflict -> 2-way, free).
__global__ __launch_bounds__(256) void k_gemm1(const __hip_bfloat16* __restrict__ A,
                                               const __hip_bfloat16* __restrict__ Bt,
                                               const float* __restrict__ b1,
                                               __hip_bfloat16* __restrict__ h2) {
    __shared__ unsigned short As[2][128 * 32];
    __shared__ unsigned short Bs[2][64 * 32];
    const int t = threadIdx.x;
    const int lane = t & 63;
    const int wave = t >> 6;
    const int lin = blockIdx.y * 64 + blockIdx.x;            // 0..1599
    const int xc  = lin & 7;                                 // XCD
    const int pos = lin >> 3;                                // 0..199
    const int bm0 = (xc * 8 + (pos & 7)) * 128;              // XCD-contig A-slab
    const int bn0 = (pos >> 3) * 64;                         // 0..24
    const int wm = (wave >> 1) * 64;                         // wave tile: 64x32
    const int wn = (wave & 1) * 32;
    const int fr = lane & 15;
    const int fq = lane >> 4;
    const int sr = t >> 2;                     // staged row 0..63 (A has +64 twin)
    // swizzled source column: LDS slot (t&3) of row sr holds global slot
    // (t&3) ^ ((sr>>1)&3). Rows sr and sr+64 share the same XOR term.
    const int scs = (((t & 3) ^ ((sr >> 1) & 3)) * 8);
    const __hip_bfloat16* ga0 = A + (size_t)(bm0 + sr) * HID + scs;
    const __hip_bfloat16* ga1 = A + (size_t)(bm0 + 64 + sr) * HID + scs;
    const __hip_bfloat16* gb0 = Bt + (size_t)(bn0 + sr) * HID + scs;
    // read side: global slot fq of row r lives in LDS slot fq ^ ((r>>1)&3);
    // (r>>1)&3 == (fr>>1)&3 for rows wm+fr+i*16 / wn+fr+j*16 (all offsets %8==0)
    const int rdx = (fr >> 1) & 3;
    const int fao = (wm + fr) * 32 + (fq ^ rdx) * 8;
    const int fbo = (wn + fr) * 32 + (fq ^ rdx) * 8;
    f32x4 acc[4][2] = {};

#define STAGE(bidx) do { \
        unsigned short* dA_ = &As[bidx][0]; unsigned short* dB_ = &Bs[bidx][0]; \
        async_ld16(ga0, dA_ + t * 8);  async_ld16(ga1, dA_ + (256 + t) * 8); \
        async_ld16(gb0, dB_ + t * 8); \
        ga0 += 32; ga1 += 32; gb0 += 32; } while (0)

    const int NKT = HID / 32;                  // 50 K-tiles
    // prologue: tiles 0 and 1 in flight (6 vmem ops/thread)
    STAGE(0);
    STAGE(1);
#pragma unroll 2
    for (int kt = 0; kt < NKT; ++kt) {
        const int p = kt & 1;
        // tile kt's 3 loads complete (tile kt+1 stays in flight); all waves sync
        if (kt < NKT - 1)
            asm volatile("s_waitcnt vmcnt(3)\n\ts_barrier" ::: "memory");
        else
            asm volatile("s_waitcnt vmcnt(0)\n\ts_barrier" ::: "memory");
        const unsigned short* fa = &As[p][fao];
        const unsigned short* fb = &Bs[p][fbo];
        bf16x8 av[4], bv[2];
#pragma unroll
        for (int i = 0; i < 4; ++i) av[i] = *(const bf16x8*)(fa + i * 16 * 32);
#pragma unroll
        for (int j = 0; j < 2; ++j) bv[j] = *(const bf16x8*)(fb + j * 16 * 32);
#pragma unroll
        for (int i = 0; i < 4; ++i)
#pragma unroll
            for (int j = 0; j < 2; ++j)
                acc[i][j] = __builtin_amdgcn_mfma_f32_16x16x32_bf16(av[i], bv[j], acc[i][j], 0, 0, 0);
        if (kt < NKT - 2) {
            // all waves finished their ds_reads of buf[p] -> safe to overwrite
            asm volatile("s_waitcnt lgkmcnt(0)\n\ts_barrier" ::: "memory");
            STAGE(p);                          // tile kt+2 (parity == p)
        }
    }
#undef STAGE

#pragma unroll
    for (int j = 0; j < 2; ++j) {
        int n = bn0 + wn + j * 16 + fr;        // < 1600 by construction
        float bias = b1[n];
#pragma unroll
        for (int i = 0; i < 4; ++i) {
#pragma unroll
            for (int r = 0; r < 4; ++r) {
                int m = bm0 + wm + i * 16 + fq * 4 + r;
                float v = acc[i][j][r] + bias;
                h2[(size_t)m * HID + n] = __float2bfloat16(fmaxf(v, 0.f));
            }
        }
    }
}

// ---------- logits + softmax (one wave per graph) ----------
__global__ void k_head(const __hip_bfloat16* __restrict__ h2, const float* __restrict__ W2,
                       const float* __restrict__ b2, float* __restrict__ out) {
    int g = blockIdx.x * 4 + (threadIdx.x >> 6);
    int lane = threadIdx.x & 63;
    const __hip_bfloat16* row = h2 + (size_t)g * HID;
    float a0 = 0.f, a1 = 0.f;
#pragma unroll
    for (int i = 0; i < 25; ++i) {
        int k = i * 64 + lane;
        float hv = __bfloat162float(row[k]);
        float2 w = ((const float2*)W2)[k];
        a0 += hv * w.x;
        a1 += hv * w.y;
    }
#pragma unroll
    for (int off = 32; off > 0; off >>= 1) {
        a0 += __shfl_down(a0, off, 64);
        a1 += __shfl_down(a1, off, 64);
    }
    if (lane == 0) {
        float l0 = a0 + b2[0], l1 = a1 + b2[1];
        float mx = fmaxf(l0, l1);
        float e0 = expf(l0 - mx), e1 = expf(l1 - mx);
        float s = e0 + e1;
        out[2 * g]     = e0 / s;
        out[2 * g + 1] = e1 / s;
    }
}

extern "C" void kernel_launch(void* const* d_in, const int* in_sizes, int n_in,
                              void* d_out, int out_size, void* d_ws, size_t ws_size,
                              hipStream_t stream) {
    const float* x  = (const float*)d_in[0];
    const int*   ei = (const int*)d_in[1];
    // d_in[2] = batch (unused; reshape handles grouping)
    const float* Wc = (const float*)d_in[3];
    const float* bc = (const float*)d_in[4];
    const float* W1 = (const float*)d_in[5];
    const float* b1 = (const float*)d_in[6];
    const float* W2 = (const float*)d_in[7];
    const float* b2 = (const float*)d_in[8];
    float* out = (float*)d_out;

    const int* srcv = ei;
    const int* dstv = ei + NE;

    // workspace layout (bytes):
    //   cur  : [0,         819200)
    //   dinv : [819200,    1638400)
    //   gcur : [1638400,   1640000)
    //   csr  : [1642496,   47517696)    int[NT*CAP]
    //   rec  : [47517696,  62263296)    unsigned[NBKT*BCAP]; dead after k_fillb
    //     hbs: [47517696,  73732096)    bf16 conv out (pre-scaled), overlays dead rec
    //     h2 : [47517696,  73732096)    bf16, overlays dead hbs (after k_gather)
    //   Hb   : [73732096,  99946496)    bf16 gather out
    //   Bt   : [99946496,  105271296)   bf16 W1^T
    char* ws = (char*)d_ws;
    int*   cur  = (int*)ws;
    float* dinv = (float*)(ws + 819200);
    int*   gcur = (int*)(ws + 1638400);
    int*   csr  = (int*)(ws + 1642496);
    unsigned* rec = (unsigned*)(ws + 47517696);
    __hip_bfloat16* hbs = (__hip_bfloat16*)(ws + 47517696);
    __hip_bfloat16* h2  = (__hip_bfloat16*)(ws + 47517696);
    __hip_bfloat16* Hb  = (__hip_bfloat16*)(ws + 73732096);
    __hip_bfloat16* Bt  = (__hip_bfloat16*)(ws + 99946496);

    k_initg    <<<1, 512, 0, stream>>>(gcur);
    k_part     <<<512, 256, 0, stream>>>(srcv, dstv, gcur, rec);
    k_fillb    <<<NBKT, 512, 0, stream>>>(gcur, rec, cur, csr, dinv);
    k_gemm_conv<<<NT / 64, 256, 0, stream>>>(x, Wc, dinv, hbs);
    k_gather   <<<NT / 4, 256, 0, stream>>>(cur, csr, dinv, hbs, bc, Hb);
    k_convW1   <<<dim3(HID / 64, HID / 64), 256, 0, stream>>>(W1, Bt);
    k_gemm1    <<<dim3(NBG / 128, HID / 64), 256, 0, stream>>>(Hb, Bt, b1, h2);
    k_head     <<<NBG / 4, 256, 0, stream>>>(h2, W2, b2, out);
}